// Round 14
// baseline (61.382 us; speedup 1.0000x reference)
//
#include <hip/hip_runtime.h>

// BahdanauAttention: B=4, LQ=512, LK=512, H=256, all f32.
//   q = query@Wq^T+bq ; k = values@Wk^T+bk
//   scores = sum_h We[h]*tanh(q+k) + be -> softmax over k -> context = attn@values
//
// Algebra:
//   tanh(x) = 1 - 2/(exp(2x)+1); be and sum(We) are additive constants on scores
//   -> softmax-invariant -> dropped. softmax(scores) = softmax(-2t) with
//   t = sum_h We_h/(1+Eq_h*Ek_h), Eq=exp2(SCALE2*q), Ek=exp2(SCALE2*k), both
//   precomputed TRANSPOSED [b][h][n] in the projection epilogue.
//   Quad-rcp packed across adjacent q-rows (v_pk_fma_f32): 14 pk + 2 rcp / 8 el.
//
// r13 post-mortem: ctx LDS-occupancy fix neutral -> ctx is latency-bound
// (depth-1 prefetch vs ~200-900cy load latency). scores grid 512 = 2 blocks/CU
// (25% occ) is the remaining scores slack (fetch volume proven free in r10).
// This round: (1) scores 32q x 128k tile, 2q x 8k/thread, grid 1024, LDS 40KB
// -> 4 blocks/CU (50% occ); (2) ctx values-prefetch depth 2.

#define SCALE2 2.8853900817779268f   // 2*log2(e)

#if defined(__has_builtin)
#if __has_builtin(__builtin_amdgcn_exp2f)
#define FEXP2(x) __builtin_amdgcn_exp2f(x)
#endif
#if __has_builtin(__builtin_amdgcn_rcpf)
#define FRCP(x) __builtin_amdgcn_rcpf(x)
#endif
#endif
#ifndef FEXP2
#define FEXP2(x) exp2f(x)
#endif
#ifndef FRCP
#define FRCP(x) (1.0f/(x))
#endif

typedef float f32x2 __attribute__((ext_vector_type(2)));

static __device__ __forceinline__ f32x2 pk2(float lo, float hi) {
  f32x2 r; r.x = lo; r.y = hi; return r;
}

// one packed quad-rcp step: 2 q-rows x 4 k-cols, accumulate into acc[4]
static __device__ __forceinline__ void pk_quad_step(
    const f32x2 qp, const float4 kv, const float w, f32x2 acc[4])
{
  const f32x2 one2 = pk2(1.0f, 1.0f);
  f32x2 x0 = __builtin_elementwise_fma(qp, pk2(kv.x, kv.x), one2);
  f32x2 x1 = __builtin_elementwise_fma(qp, pk2(kv.y, kv.y), one2);
  f32x2 x2 = __builtin_elementwise_fma(qp, pk2(kv.z, kv.z), one2);
  f32x2 x3 = __builtin_elementwise_fma(qp, pk2(kv.w, kv.w), one2);
  f32x2 p01 = x0 * x1, p23 = x2 * x3, P = p01 * p23;
  f32x2 rr; rr.x = FRCP(P.x); rr.y = FRCP(P.y);
  f32x2 wr = rr * w;
  f32x2 sw = wr * p23, uw = wr * p01;
  acc[0] = __builtin_elementwise_fma(sw, x1, acc[0]);
  acc[1] = __builtin_elementwise_fma(sw, x0, acc[1]);
  acc[2] = __builtin_elementwise_fma(uw, x3, acc[2]);
  acc[3] = __builtin_elementwise_fma(uw, x2, acc[3]);
}

// Fused projections. blockIdx.z = 0: EqT[b][o][q] = exp2(SCALE2*(query@Wq^T+bq))
//                    blockIdx.z = 1: EkT[b][o][k] = exp2(SCALE2*(values@Wk^T+bk))
__global__ __launch_bounds__(512) void proj_kernel(
    const float* __restrict__ Q, const float* __restrict__ V,
    const float* __restrict__ Wq, const float* __restrict__ bq,
    const float* __restrict__ Wk, const float* __restrict__ bk,
    float* __restrict__ EqT, float* __restrict__ EkT)
{
  const int n0 = blockIdx.x * 64;
  const int o0 = blockIdx.y * 64;
  const bool isK = (blockIdx.z == 1);
  const float* X    = isK ? V  : Q;
  const float* W    = isK ? Wk : Wq;
  const float* bias = isK ? bk : bq;
  const int t  = threadIdx.x;
  const int tx = t & 15;        // o quad
  const int ty = t >> 4;        // 0..31 : n pair
  __shared__ float Xst[32][68]; // [h][n]
  __shared__ float Wst[32][68]; // [h][o]
  float acc[2][4] = {};
  const int sr = t >> 3, sc = (t & 7) << 2;   // staging coords: 64 rows x 32 cols
  float4 xv = *(const float4*)(X + (size_t)(n0 + sr) * 256 + sc);
  float4 wv = *(const float4*)(W + (size_t)(o0 + sr) * 256 + sc);
  for (int h0 = 0; h0 < 256; h0 += 32) {
    __syncthreads();
    Xst[sc  ][sr] = xv.x; Xst[sc+1][sr] = xv.y; Xst[sc+2][sr] = xv.z; Xst[sc+3][sr] = xv.w;
    Wst[sc  ][sr] = wv.x; Wst[sc+1][sr] = wv.y; Wst[sc+2][sr] = wv.z; Wst[sc+3][sr] = wv.w;
    __syncthreads();
    if (h0 < 224) {   // prefetch next chunk during compute
      xv = *(const float4*)(X + (size_t)(n0 + sr) * 256 + h0 + 32 + sc);
      wv = *(const float4*)(W + (size_t)(o0 + sr) * 256 + h0 + 32 + sc);
    }
#pragma unroll 8
    for (int hh = 0; hh < 32; ++hh) {
      float2 a  = *(const float2*)&Xst[hh][ty*2];
      float4 bb = *(const float4*)&Wst[hh][tx*4];
      acc[0][0] = fmaf(a.x, bb.x, acc[0][0]); acc[0][1] = fmaf(a.x, bb.y, acc[0][1]);
      acc[0][2] = fmaf(a.x, bb.z, acc[0][2]); acc[0][3] = fmaf(a.x, bb.w, acc[0][3]);
      acc[1][0] = fmaf(a.y, bb.x, acc[1][0]); acc[1][1] = fmaf(a.y, bb.y, acc[1][1]);
      acc[1][2] = fmaf(a.y, bb.z, acc[1][2]); acc[1][3] = fmaf(a.y, bb.w, acc[1][3]);
    }
  }
  const float4 bv = *(const float4*)(bias + o0 + tx*4);
  float e[2][4];
#pragma unroll
  for (int i = 0; i < 2; ++i) {
    e[i][0] = FEXP2(SCALE2 * (acc[i][0] + bv.x));
    e[i][1] = FEXP2(SCALE2 * (acc[i][1] + bv.y));
    e[i][2] = FEXP2(SCALE2 * (acc[i][2] + bv.z));
    e[i][3] = FEXP2(SCALE2 * (acc[i][3] + bv.w));
  }
  // transposed store for BOTH operands: outT[b][o][n]
  float* outT = isK ? EkT : EqT;
  const int b  = n0 >> 9;
  const int nl = (n0 & 511) + ty*2;
#pragma unroll
  for (int j = 0; j < 4; ++j) {
    float2 st = {e[0][j], e[1][j]};
    *(float2*)(outT + (size_t)b*131072 + (size_t)(o0 + tx*4 + j)*512 + nl) = st;
  }
}

// Partial t over a 64-h slice: pt[half][b][q][k] = sum_h We/(1+Eq*Ek).
// tile 32q x 128k x 64h, 256 threads, thread = 2q x 8k (one packed q-pair).
// grid 1024 = 4kt x 16qt x 16z; LDS 40KB dbuf -> 4 blocks/CU (16 waves/CU).
__global__ __launch_bounds__(256) void scores_kernel(
    const float* __restrict__ EqT, const float* __restrict__ EkT,
    const float* __restrict__ We, float* __restrict__ pt)
{
  const int flat = blockIdx.x;
  const int kt = flat & 3;           // 0..3  : 128-k tile
  const int qt = (flat >> 2) & 15;   // 0..15 : 32-q tile
  const int z  = flat >> 6;          // 0..15 : (b,half)
  const int b = z >> 2, half = z & 3;
  const int h0 = half * 64;
  const int t  = threadIdx.x;
  const int qr = t >> 4;             // 0..15 : q-pair index
  const int kr = t & 15;             // 0..15 : k quad index (and kr+16)

  __shared__ float  qs [2][32][32];  // [buf][h][q]     4KB each
  __shared__ float4 ks4[2][32][32];  // [buf][h][kquad] 16KB each

  const float* eqb = EqT + (size_t)b*131072 + (size_t)h0*512 + qt*32;
  const float* ekb = EkT + (size_t)b*131072 + (size_t)h0*512 + kt*128;

  // staging: q = 256 float4/chunk (1/thread), k = 1024 (4/thread)
  const int rs = t >> 3;             // 0..31 : h-row
  const int cq = (t & 7) * 4;        // q float offset
  const int sk = (t & 7) * 4;        // k float4 slots sk..sk+3

  // ---- load chunk 0
  float4 aq = *(const float4*)(eqb + (size_t)rs*512 + cq);
  float4 ak[4];
#pragma unroll
  for (int j = 0; j < 4; ++j)
    ak[j] = *(const float4*)(ekb + (size_t)rs*512 + (sk+j)*4);
  *(float4*)&qs[0][rs][cq] = aq;
#pragma unroll
  for (int j = 0; j < 4; ++j) ks4[0][rs][sk+j] = ak[j];

  // ---- issue chunk 1 loads (land during compute of chunk 0)
  float4 bq = *(const float4*)(eqb + (size_t)(32+rs)*512 + cq);
  float4 bk[4];
#pragma unroll
  for (int j = 0; j < 4; ++j)
    bk[j] = *(const float4*)(ekb + (size_t)(32+rs)*512 + (sk+j)*4);

  __syncthreads();                   // buf 0 ready

  f32x2 acc[2][4];                   // [kchain][4k]
#pragma unroll
  for (int c = 0; c < 2; ++c)
#pragma unroll
    for (int j = 0; j < 4; ++j) acc[c][j] = pk2(0.f, 0.f);

#pragma unroll 4
  for (int hh = 0; hh < 32; ++hh) {          // compute buf 0 (h 0..31)
    const float w = We[h0 + hh];
    const f32x2 qp  = *(const f32x2*)&qs[0][hh][qr*2];   // b64: the q-pair
    const float4 kv0 = ks4[0][hh][kr];
    const float4 kv1 = ks4[0][hh][kr + 16];
    pk_quad_step(qp, kv0, w, acc[0]);
    pk_quad_step(qp, kv1, w, acc[1]);
  }

  // write chunk 1 into buf 1 (vmcnt wait here; latency already hidden)
  *(float4*)&qs[1][rs][cq] = bq;
#pragma unroll
  for (int j = 0; j < 4; ++j) ks4[1][rs][sk+j] = bk[j];
  __syncthreads();                   // buf 1 ready

#pragma unroll 4
  for (int hh = 0; hh < 32; ++hh) {          // compute buf 1 (h 32..63)
    const float w = We[h0 + 32 + hh];
    const f32x2 qp  = *(const f32x2*)&qs[1][hh][qr*2];
    const float4 kv0 = ks4[1][hh][kr];
    const float4 kv1 = ks4[1][hh][kr + 16];
    pk_quad_step(qp, kv0, w, acc[0]);
    pk_quad_step(qp, kv1, w, acc[1]);
  }

  // epilogue: .x = q-row qr*2, .y = q-row qr*2+1; chain c -> cols +64*c
  float* sout = pt + (size_t)half*1048576
                   + (size_t)(b*512 + qt*32 + qr*2)*512 + kt*128 + kr*4;
  float4 r0c0 = {acc[0][0].x, acc[0][1].x, acc[0][2].x, acc[0][3].x};
  float4 r0c1 = {acc[1][0].x, acc[1][1].x, acc[1][2].x, acc[1][3].x};
  float4 r1c0 = {acc[0][0].y, acc[0][1].y, acc[0][2].y, acc[0][3].y};
  float4 r1c1 = {acc[1][0].y, acc[1][1].y, acc[1][2].y, acc[1][3].y};
  *(float4*)(sout)            = r0c0;
  *(float4*)(sout + 64)       = r0c1;
  *(float4*)(sout + 512)      = r1c0;
  *(float4*)(sout + 512 + 64) = r1c1;
}

// Fused softmax + context. 8 rows/block, 256 blocks, 512 threads.
// Stage ts = sum of 4 h-partials; wave w softmaxes row w (writes attn out).
// ctx phase: wave w = (ks = w&3, hh = w>>2) -> k-slice x h-half; lane bit s
// sub-splits k; shfl_xor(32) fold; red[8][8][128] = 32KB. values prefetch
// DEPTH 2 (cv/nv/mv) so each load is issued ~2 compute windows (~512cy) ahead.
__global__ __launch_bounds__(512) void ctx_kernel(
    const float* __restrict__ values, const float* __restrict__ pt,
    float* __restrict__ attn, float* __restrict__ ctx)
{
  const int t    = threadIdx.x;
  const int row0 = blockIdx.x * 8;
  const int b    = row0 >> 9;
  __shared__ float ts[8][512];        // 16KB: summed t -> normalized attn
  __shared__ float red[8][8][128];    // 32KB: per-wave partial ctx (h-half wide)

  // stage ts = pt0+pt1+pt2+pt3 (8 rows x 512)
#pragma unroll
  for (int rep = 0; rep < 2; ++rep) {
    int idx = rep*512 + t;
    int r = idx >> 7, c = (idx & 127) << 2;
    size_t off = (size_t)(row0 + r)*512 + c;
    float4 v0 = *(const float4*)(pt + off);
    float4 v1 = *(const float4*)(pt + 1048576 + off);
    float4 v2 = *(const float4*)(pt + 2097152 + off);
    float4 v3 = *(const float4*)(pt + 3145728 + off);
    float4 s = {v0.x+v1.x+v2.x+v3.x, v0.y+v1.y+v2.y+v3.y,
                v0.z+v1.z+v2.z+v3.z, v0.w+v1.w+v2.w+v3.w};
    *(float4*)&ts[r][c] = s;
  }
  __syncthreads();

  const int w = t >> 6, j = t & 63;   // wave id, lane
  // softmax(-2t): wave w -> row w; exponent (mn - t)*SCALE2
  {
    float v[8];
    float mn = 1e30f;
#pragma unroll
    for (int i = 0; i < 8; ++i) { v[i] = ts[w][j + 64*i]; mn = fminf(mn, v[i]); }
#pragma unroll
    for (int off = 32; off > 0; off >>= 1) mn = fminf(mn, __shfl_xor(mn, off, 64));
    float sum = 0.f;
#pragma unroll
    for (int i = 0; i < 8; ++i) { v[i] = FEXP2((mn - v[i]) * SCALE2); sum += v[i]; }
#pragma unroll
    for (int off = 32; off > 0; off >>= 1) sum += __shfl_xor(sum, off, 64);
    const float inv = 1.0f / sum;
    float* gp = attn + (size_t)(row0 + w) * 512 + j;
#pragma unroll
    for (int i = 0; i < 8; ++i) {
      float p = v[i] * inv;
      ts[w][j + 64*i] = p;      // wave-local row: no cross-wave dependency yet
      gp[64*i] = p;             // coalesced attention output
    }
  }
  __syncthreads();              // all rows of ts normalized

  // context partials: wave w -> (ks = w&3, hh = w>>2); lane: s = j>>5 (k sub),
  // jq = j&31 (h-quad). Thread covers 8 rows x 64 k x 4 h.
  const int ks = w & 3, hh = w >> 2;
  const int s  = j >> 5, jq = j & 31;
  const int k0 = ks*128 + s*64;
  const int h4 = hh*128 + jq*4;
  const float* vwb = values + (size_t)b*131072 + (size_t)k0*256 + h4;
  float4 acc[8];
#pragma unroll
  for (int r = 0; r < 8; ++r) acc[r] = (float4){0,0,0,0};

  float4 cv[4], nv[4], mv[4];
#pragma unroll
  for (int jj = 0; jj < 4; ++jj) cv[jj] = *(const float4*)(vwb + (size_t)jj*256);
#pragma unroll
  for (int jj = 0; jj < 4; ++jj) nv[jj] = *(const float4*)(vwb + (size_t)(4 + jj)*256);

  for (int kq = 0; kq < 16; ++kq) {        // 16 quads of this thread's 64 k
    if (kq < 14) {
#pragma unroll
      for (int jj = 0; jj < 4; ++jj)
        mv[jj] = *(const float4*)(vwb + (size_t)((kq+2)*4 + jj)*256);
    }
    float4 a[8];
#pragma unroll
    for (int r = 0; r < 8; ++r) a[r] = *(const float4*)&ts[r][k0 + kq*4]; // bcast
#pragma unroll
    for (int jj = 0; jj < 4; ++jj) {
      float4 v4 = cv[jj];
#pragma unroll
      for (int r = 0; r < 8; ++r) {
        float ar = (jj == 0) ? a[r].x : (jj == 1) ? a[r].y : (jj == 2) ? a[r].z : a[r].w;
        acc[r].x = fmaf(ar, v4.x, acc[r].x);
        acc[r].y = fmaf(ar, v4.y, acc[r].y);
        acc[r].z = fmaf(ar, v4.z, acc[r].z);
        acc[r].w = fmaf(ar, v4.w, acc[r].w);
      }
    }
#pragma unroll
    for (int jj = 0; jj < 4; ++jj) { cv[jj] = nv[jj]; nv[jj] = mv[jj]; }
  }

  // fold the two k sub-slices (lanes j and j^32 share the same (r,h4))
#pragma unroll
  for (int r = 0; r < 8; ++r) {
    acc[r].x += __shfl_xor(acc[r].x, 32);
    acc[r].y += __shfl_xor(acc[r].y, 32);
    acc[r].z += __shfl_xor(acc[r].z, 32);
    acc[r].w += __shfl_xor(acc[r].w, 32);
  }
  if (s == 0) {                        // lanes 0..31 write the folded partial
#pragma unroll
    for (int r = 0; r < 8; ++r) *(float4*)&red[w][r][jq*4] = acc[r];
  }
  __syncthreads();

  // final: sum 4 ks-partials per h-half. thread -> (row rr, h-quad)
  {
    const int rr = t >> 6;             // 0..7 (wave-uniform)
    const int jj = t & 63;
    const int h2 = jj >> 5;            // h-half
    const int lh = (jj & 31) << 2;     // local h offset in half
    float4 s0 = *(const float4*)&red[h2*4 + 0][rr][lh];
    float4 s1 = *(const float4*)&red[h2*4 + 1][rr][lh];
    float4 s2 = *(const float4*)&red[h2*4 + 2][rr][lh];
    float4 s3 = *(const float4*)&red[h2*4 + 3][rr][lh];
    float4 o = {s0.x+s1.x+s2.x+s3.x, s0.y+s1.y+s2.y+s3.y,
                s0.z+s1.z+s2.z+s3.z, s0.w+s1.w+s2.w+s3.w};
    *(float4*)(ctx + (size_t)(row0 + rr)*256 + h2*128 + lh) = o;
  }
}

extern "C" void kernel_launch(void* const* d_in, const int* in_sizes, int n_in,
                              void* d_out, int out_size, void* d_ws, size_t ws_size,
                              hipStream_t stream)
{
  const float* query  = (const float*)d_in[0];
  const float* values = (const float*)d_in[1];
  const float* Wq     = (const float*)d_in[2];
  const float* bq     = (const float*)d_in[3];
  const float* Wk     = (const float*)d_in[4];
  const float* bk     = (const float*)d_in[5];
  const float* We     = (const float*)d_in[6];
  // d_in[7] = be: additive constant on scores -> softmax-invariant -> unused.

  float* ctx  = (float*)d_out;            // 4*512*256 floats
  float* attn = ctx + 4*512*256;          // 4*512*512 floats (final attention)
  float* EqT  = (float*)d_ws;             // [b][h][q], 524288 floats (2MB)
  float* EkT  = EqT + 524288;             // [b][h][k], 524288 floats (2MB)
  float* pt   = EkT + 524288;             // 4 h-partials, 4x 1048576 floats (16MB)

  proj_kernel  <<<dim3(32, 4, 2), 512, 0, stream>>>(query, values, Wq, bq, Wk, bk, EqT, EkT);
  scores_kernel<<<1024, 256, 0, stream>>>(EqT, EkT, We, pt);
  ctx_kernel   <<<256, 512, 0, stream>>>(values, pt, attn, ctx);
}

// Round 15
// 60.013 us; speedup vs baseline: 1.0228x; 1.0228x over previous
//
#include <hip/hip_runtime.h>

// BahdanauAttention: B=4, LQ=512, LK=512, H=256, all f32.
//   q = query@Wq^T+bq ; k = values@Wk^T+bk
//   scores = sum_h We[h]*tanh(q+k) + be -> softmax over k -> context = attn@values
//
// Algebra:
//   tanh(x) = 1 - 2/(exp(2x)+1); be and sum(We) are additive constants on scores
//   -> softmax-invariant -> dropped. softmax(scores) = softmax(-2t) with
//   t = sum_h We_h/(1+Eq_h*Ek_h), Eq=exp2(SCALE2*q), Ek=exp2(SCALE2*k), both
//   precomputed TRANSPOSED [b][h][n] in the projection epilogue.
//   Quad-rcp packed across adjacent q-rows (v_pk_fma_f32): 14 pk + 2 rcp / 8 el.
//
// r13/r14 post-mortem: ctx remap, depth-2 prefetch, 2x scores occupancy all
// neutral -> scores is VALU-issue-COUNT limited, busy ~1.7x the packed ideal.
// Candidate excess: pk2(kv.c,kv.c) element-constructed splats may defeat the
// op_sel fold. This round: exact r12 geometry (best measured, 60.2us) + splats
// expressed as __builtin_shufflevector(kv01,kv01,i,i) of f32x2 halves (the
// canonical single-source splat the GCN backend folds into op_sel).

#define SCALE2 2.8853900817779268f   // 2*log2(e)

#if defined(__has_builtin)
#if __has_builtin(__builtin_amdgcn_exp2f)
#define FEXP2(x) __builtin_amdgcn_exp2f(x)
#endif
#if __has_builtin(__builtin_amdgcn_rcpf)
#define FRCP(x) __builtin_amdgcn_rcpf(x)
#endif
#endif
#ifndef FEXP2
#define FEXP2(x) exp2f(x)
#endif
#ifndef FRCP
#define FRCP(x) (1.0f/(x))
#endif

typedef float f32x2 __attribute__((ext_vector_type(2)));

static __device__ __forceinline__ f32x2 pk2(float lo, float hi) {
  f32x2 r; r.x = lo; r.y = hi; return r;
}

// one packed quad-rcp step: 2 q-rows x 4 k-cols, accumulate into acc[4].
// k comes as two f32x2 halves; broadcasts are canonical splat shuffles
// (op_sel-foldable on v_pk_* consumers).
static __device__ __forceinline__ void pk_quad_step(
    const f32x2 qp, const f32x2 kv01, const f32x2 kv23, const float w,
    f32x2 acc[4])
{
  const f32x2 one2 = pk2(1.0f, 1.0f);
  const f32x2 k0 = __builtin_shufflevector(kv01, kv01, 0, 0);
  const f32x2 k1 = __builtin_shufflevector(kv01, kv01, 1, 1);
  const f32x2 k2 = __builtin_shufflevector(kv23, kv23, 0, 0);
  const f32x2 k3 = __builtin_shufflevector(kv23, kv23, 1, 1);
  f32x2 x0 = __builtin_elementwise_fma(qp, k0, one2);
  f32x2 x1 = __builtin_elementwise_fma(qp, k1, one2);
  f32x2 x2 = __builtin_elementwise_fma(qp, k2, one2);
  f32x2 x3 = __builtin_elementwise_fma(qp, k3, one2);
  f32x2 p01 = x0 * x1, p23 = x2 * x3, P = p01 * p23;
  f32x2 rr; rr.x = FRCP(P.x); rr.y = FRCP(P.y);
  f32x2 wr = rr * w;
  f32x2 sw = wr * p23, uw = wr * p01;
  acc[0] = __builtin_elementwise_fma(sw, x1, acc[0]);
  acc[1] = __builtin_elementwise_fma(sw, x0, acc[1]);
  acc[2] = __builtin_elementwise_fma(uw, x3, acc[2]);
  acc[3] = __builtin_elementwise_fma(uw, x2, acc[3]);
}

// Fused projections. blockIdx.z = 0: EqT[b][o][q] = exp2(SCALE2*(query@Wq^T+bq))
//                    blockIdx.z = 1: EkT[b][o][k] = exp2(SCALE2*(values@Wk^T+bk))
__global__ __launch_bounds__(512) void proj_kernel(
    const float* __restrict__ Q, const float* __restrict__ V,
    const float* __restrict__ Wq, const float* __restrict__ bq,
    const float* __restrict__ Wk, const float* __restrict__ bk,
    float* __restrict__ EqT, float* __restrict__ EkT)
{
  const int n0 = blockIdx.x * 64;
  const int o0 = blockIdx.y * 64;
  const bool isK = (blockIdx.z == 1);
  const float* X    = isK ? V  : Q;
  const float* W    = isK ? Wk : Wq;
  const float* bias = isK ? bk : bq;
  const int t  = threadIdx.x;
  const int tx = t & 15;        // o quad
  const int ty = t >> 4;        // 0..31 : n pair
  __shared__ float Xst[32][68]; // [h][n]
  __shared__ float Wst[32][68]; // [h][o]
  float acc[2][4] = {};
  const int sr = t >> 3, sc = (t & 7) << 2;   // staging coords: 64 rows x 32 cols
  float4 xv = *(const float4*)(X + (size_t)(n0 + sr) * 256 + sc);
  float4 wv = *(const float4*)(W + (size_t)(o0 + sr) * 256 + sc);
  for (int h0 = 0; h0 < 256; h0 += 32) {
    __syncthreads();
    Xst[sc  ][sr] = xv.x; Xst[sc+1][sr] = xv.y; Xst[sc+2][sr] = xv.z; Xst[sc+3][sr] = xv.w;
    Wst[sc  ][sr] = wv.x; Wst[sc+1][sr] = wv.y; Wst[sc+2][sr] = wv.z; Wst[sc+3][sr] = wv.w;
    __syncthreads();
    if (h0 < 224) {   // prefetch next chunk during compute
      xv = *(const float4*)(X + (size_t)(n0 + sr) * 256 + h0 + 32 + sc);
      wv = *(const float4*)(W + (size_t)(o0 + sr) * 256 + h0 + 32 + sc);
    }
#pragma unroll 8
    for (int hh = 0; hh < 32; ++hh) {
      float2 a  = *(const float2*)&Xst[hh][ty*2];
      float4 bb = *(const float4*)&Wst[hh][tx*4];
      acc[0][0] = fmaf(a.x, bb.x, acc[0][0]); acc[0][1] = fmaf(a.x, bb.y, acc[0][1]);
      acc[0][2] = fmaf(a.x, bb.z, acc[0][2]); acc[0][3] = fmaf(a.x, bb.w, acc[0][3]);
      acc[1][0] = fmaf(a.y, bb.x, acc[1][0]); acc[1][1] = fmaf(a.y, bb.y, acc[1][1]);
      acc[1][2] = fmaf(a.y, bb.z, acc[1][2]); acc[1][3] = fmaf(a.y, bb.w, acc[1][3]);
    }
  }
  const float4 bv = *(const float4*)(bias + o0 + tx*4);
  float e[2][4];
#pragma unroll
  for (int i = 0; i < 2; ++i) {
    e[i][0] = FEXP2(SCALE2 * (acc[i][0] + bv.x));
    e[i][1] = FEXP2(SCALE2 * (acc[i][1] + bv.y));
    e[i][2] = FEXP2(SCALE2 * (acc[i][2] + bv.z));
    e[i][3] = FEXP2(SCALE2 * (acc[i][3] + bv.w));
  }
  // transposed store for BOTH operands: outT[b][o][n]
  float* outT = isK ? EkT : EqT;
  const int b  = n0 >> 9;
  const int nl = (n0 & 511) + ty*2;
#pragma unroll
  for (int j = 0; j < 4; ++j) {
    float2 st = {e[0][j], e[1][j]};
    *(float2*)(outT + (size_t)b*131072 + (size_t)(o0 + tx*4 + j)*512 + nl) = st;
  }
}

// Partial t over a 64-h slice: pt[half][b][q][k] = sum_h We/(1+Eq*Ek).
// tile 64q x 128k x 64h, 256 threads, thread = 4q x 8k. Packed fp32 inner math.
// grid 512 = 4kt x 8qt x 16z. LDS 48KB dbuf.
__global__ __launch_bounds__(256) void scores_kernel(
    const float* __restrict__ EqT, const float* __restrict__ EkT,
    const float* __restrict__ We, float* __restrict__ pt)
{
  const int flat = blockIdx.x;
  const int kt = flat & 3;           // 0..3  : 128-k tile
  const int qt = (flat >> 2) & 7;    // 0..7  : 64-q tile
  const int z  = flat >> 5;          // 0..15 : (b,half)
  const int b = z >> 2, half = z & 3;
  const int h0 = half * 64;
  const int t  = threadIdx.x;
  const int qr = t >> 4;             // 0..15 : q quad index
  const int kr = t & 15;             // 0..15 : k quad index (and kr+16)

  __shared__ float4 qs4[2][32][16];  // [buf][h][qquad] 8KB each
  __shared__ float4 ks4[2][32][32];  // [buf][h][kquad] 16KB each

  const float* eqb = EqT + (size_t)b*131072 + (size_t)h0*512 + qt*64;
  const float* ekb = EkT + (size_t)b*131072 + (size_t)h0*512 + kt*128;

  // staging coords: q = 512 float4/chunk (2/thread), k = 1024 (4/thread)
  const int rs = t >> 3;             // 0..31 : h-row
  const int sq = (t & 7) * 2;        // q float4 slots sq, sq+1
  const int sk = (t & 7) * 4;        // k float4 slots sk..sk+3

  // ---- load chunk 0
  float4 aq0 = *(const float4*)(eqb + (size_t)rs*512 + (sq  )*4);
  float4 aq1 = *(const float4*)(eqb + (size_t)rs*512 + (sq+1)*4);
  float4 ak[4];
#pragma unroll
  for (int j = 0; j < 4; ++j)
    ak[j] = *(const float4*)(ekb + (size_t)rs*512 + (sk+j)*4);
  qs4[0][rs][sq] = aq0; qs4[0][rs][sq+1] = aq1;
#pragma unroll
  for (int j = 0; j < 4; ++j) ks4[0][rs][sk+j] = ak[j];

  // ---- issue chunk 1 loads (land during compute of chunk 0)
  float4 bq0 = *(const float4*)(eqb + (size_t)(32+rs)*512 + (sq  )*4);
  float4 bq1 = *(const float4*)(eqb + (size_t)(32+rs)*512 + (sq+1)*4);
  float4 bk[4];
#pragma unroll
  for (int j = 0; j < 4; ++j)
    bk[j] = *(const float4*)(ekb + (size_t)(32+rs)*512 + (sk+j)*4);

  __syncthreads();                   // buf 0 ready

  f32x2 acc[2][2][4];                // [qpair][kchain][4k]
#pragma unroll
  for (int p = 0; p < 2; ++p)
#pragma unroll
    for (int c = 0; c < 2; ++c)
#pragma unroll
      for (int j = 0; j < 4; ++j) acc[p][c][j] = pk2(0.f, 0.f);

#pragma unroll 4
  for (int hh = 0; hh < 32; ++hh) {          // compute buf 0 (h 0..31)
    const float w = We[h0 + hh];
    const float4 qv  = qs4[0][hh][qr];
    const float4 kv0 = ks4[0][hh][kr];
    const float4 kv1 = ks4[0][hh][kr + 16];
    const f32x2 qlo = pk2(qv.x, qv.y), qhi = pk2(qv.z, qv.w);
    const f32x2 k0a = pk2(kv0.x, kv0.y), k0b = pk2(kv0.z, kv0.w);
    const f32x2 k1a = pk2(kv1.x, kv1.y), k1b = pk2(kv1.z, kv1.w);
    pk_quad_step(qlo, k0a, k0b, w, acc[0][0]);
    pk_quad_step(qlo, k1a, k1b, w, acc[0][1]);
    pk_quad_step(qhi, k0a, k0b, w, acc[1][0]);
    pk_quad_step(qhi, k1a, k1b, w, acc[1][1]);
  }

  // write chunk 1 into buf 1 (vmcnt wait here; latency already hidden)
  qs4[1][rs][sq] = bq0; qs4[1][rs][sq+1] = bq1;
#pragma unroll
  for (int j = 0; j < 4; ++j) ks4[1][rs][sk+j] = bk[j];
  __syncthreads();                   // buf 1 ready

#pragma unroll 4
  for (int hh = 0; hh < 32; ++hh) {          // compute buf 1 (h 32..63)
    const float w = We[h0 + 32 + hh];
    const float4 qv  = qs4[1][hh][qr];
    const float4 kv0 = ks4[1][hh][kr];
    const float4 kv1 = ks4[1][hh][kr + 16];
    const f32x2 qlo = pk2(qv.x, qv.y), qhi = pk2(qv.z, qv.w);
    const f32x2 k0a = pk2(kv0.x, kv0.y), k0b = pk2(kv0.z, kv0.w);
    const f32x2 k1a = pk2(kv1.x, kv1.y), k1b = pk2(kv1.z, kv1.w);
    pk_quad_step(qlo, k0a, k0b, w, acc[0][0]);
    pk_quad_step(qlo, k1a, k1b, w, acc[0][1]);
    pk_quad_step(qhi, k0a, k0b, w, acc[1][0]);
    pk_quad_step(qhi, k1a, k1b, w, acc[1][1]);
  }

  // epilogue: unpack pairs. q-row i = p*2+s (q = qt*64+qr*4+i);
  // chain 0 -> cols kt*128+kr*4, chain 1 -> +64.
  float* sout = pt + (size_t)half*1048576
                   + (size_t)(b*512 + qt*64 + qr*4)*512 + kt*128 + kr*4;
#pragma unroll
  for (int p = 0; p < 2; ++p) {
#pragma unroll
    for (int s = 0; s < 2; ++s) {
      const int i = p*2 + s;
      float4 s0, s1;
      if (s == 0) {
        s0 = (float4){acc[p][0][0].x, acc[p][0][1].x, acc[p][0][2].x, acc[p][0][3].x};
        s1 = (float4){acc[p][1][0].x, acc[p][1][1].x, acc[p][1][2].x, acc[p][1][3].x};
      } else {
        s0 = (float4){acc[p][0][0].y, acc[p][0][1].y, acc[p][0][2].y, acc[p][0][3].y};
        s1 = (float4){acc[p][1][0].y, acc[p][1][1].y, acc[p][1][2].y, acc[p][1][3].y};
      }
      *(float4*)(sout + (size_t)i*512) = s0;
      *(float4*)(sout + (size_t)i*512 + 64) = s1;
    }
  }
}

// Fused softmax + context. 8 rows/block, 256 blocks, 512 threads.
// Stage ts = sum of 4 h-partials; wave w softmaxes row w (writes attn out);
// then wave w takes k-slice [w*64,(w+1)*64): acc[8] row-accumulators in
// registers, values read once per block straight from global (b128, L2-hot),
// attn via uniform b128 LDS broadcasts; cross-wave reduction through red[].
__global__ __launch_bounds__(512) void ctx_kernel(
    const float* __restrict__ values, const float* __restrict__ pt,
    float* __restrict__ attn, float* __restrict__ ctx)
{
  const int t    = threadIdx.x;
  const int row0 = blockIdx.x * 8;
  const int b    = row0 >> 9;
  __shared__ float ts[8][512];        // 16KB: summed t -> normalized attn
  __shared__ float red[8][8][256];    // 64KB: per-wave partial ctx

  // stage ts = pt0+pt1+pt2+pt3 (8 rows x 512)
#pragma unroll
  for (int rep = 0; rep < 2; ++rep) {
    int idx = rep*512 + t;
    int r = idx >> 7, c = (idx & 127) << 2;
    size_t off = (size_t)(row0 + r)*512 + c;
    float4 v0 = *(const float4*)(pt + off);
    float4 v1 = *(const float4*)(pt + 1048576 + off);
    float4 v2 = *(const float4*)(pt + 2097152 + off);
    float4 v3 = *(const float4*)(pt + 3145728 + off);
    float4 s = {v0.x+v1.x+v2.x+v3.x, v0.y+v1.y+v2.y+v3.y,
                v0.z+v1.z+v2.z+v3.z, v0.w+v1.w+v2.w+v3.w};
    *(float4*)&ts[r][c] = s;
  }
  __syncthreads();

  const int w = t >> 6, j = t & 63;   // wave id, lane
  // softmax(-2t): wave w -> row w; exponent (mn - t)*SCALE2
  {
    float v[8];
    float mn = 1e30f;
#pragma unroll
    for (int i = 0; i < 8; ++i) { v[i] = ts[w][j + 64*i]; mn = fminf(mn, v[i]); }
#pragma unroll
    for (int off = 32; off > 0; off >>= 1) mn = fminf(mn, __shfl_xor(mn, off, 64));
    float sum = 0.f;
#pragma unroll
    for (int i = 0; i < 8; ++i) { v[i] = FEXP2((mn - v[i]) * SCALE2); sum += v[i]; }
#pragma unroll
    for (int off = 32; off > 0; off >>= 1) sum += __shfl_xor(sum, off, 64);
    const float inv = 1.0f / sum;
    float* gp = attn + (size_t)(row0 + w) * 512 + j;
#pragma unroll
    for (int i = 0; i < 8; ++i) {
      float p = v[i] * inv;
      ts[w][j + 64*i] = p;      // wave-local row: no cross-wave dependency yet
      gp[64*i] = p;             // coalesced attention output
    }
  }
  __syncthreads();              // all rows of ts normalized

  // context partials: wave w -> k in [w*64, w*64+64), lane -> 4 h-cols
  const int h4 = j << 2;
  const int wk0 = w * 64;
  const float* vwb = values + (size_t)b*131072 + (size_t)wk0*256 + h4;
  float4 acc[8];
#pragma unroll
  for (int r = 0; r < 8; ++r) acc[r] = (float4){0,0,0,0};

  float4 cv[4], nv[4];
#pragma unroll
  for (int jj = 0; jj < 4; ++jj) cv[jj] = *(const float4*)(vwb + (size_t)jj*256);

  for (int kq = 0; kq < 16; ++kq) {        // 16 quads of k
    if (kq < 15) {
#pragma unroll
      for (int jj = 0; jj < 4; ++jj)
        nv[jj] = *(const float4*)(vwb + (size_t)((kq+1)*4 + jj)*256);
    }
    float4 a[8];
#pragma unroll
    for (int r = 0; r < 8; ++r) a[r] = *(const float4*)&ts[r][wk0 + kq*4]; // b128 bcast
#pragma unroll
    for (int jj = 0; jj < 4; ++jj) {
      float4 v4 = cv[jj];
#pragma unroll
      for (int r = 0; r < 8; ++r) {
        float ar = (jj == 0) ? a[r].x : (jj == 1) ? a[r].y : (jj == 2) ? a[r].z : a[r].w;
        acc[r].x = fmaf(ar, v4.x, acc[r].x);
        acc[r].y = fmaf(ar, v4.y, acc[r].y);
        acc[r].z = fmaf(ar, v4.z, acc[r].z);
        acc[r].w = fmaf(ar, v4.w, acc[r].w);
      }
    }
#pragma unroll
    for (int jj = 0; jj < 4; ++jj) cv[jj] = nv[jj];
  }

  // write per-wave partials, reduce across waves
#pragma unroll
  for (int r = 0; r < 8; ++r) *(float4*)&red[w][r][h4] = acc[r];
  __syncthreads();
  {
    const int rr = t >> 6;               // row 0..7 (wave-uniform)
    const int hh4 = (t & 63) << 2;
    float4 s = *(const float4*)&red[0][rr][hh4];
#pragma unroll
    for (int ww = 1; ww < 8; ++ww) {
      float4 p = *(const float4*)&red[ww][rr][hh4];
      s.x += p.x; s.y += p.y; s.z += p.z; s.w += p.w;
    }
    *(float4*)(ctx + (size_t)(row0 + rr)*256 + hh4) = s;
  }
}

extern "C" void kernel_launch(void* const* d_in, const int* in_sizes, int n_in,
                              void* d_out, int out_size, void* d_ws, size_t ws_size,
                              hipStream_t stream)
{
  const float* query  = (const float*)d_in[0];
  const float* values = (const float*)d_in[1];
  const float* Wq     = (const float*)d_in[2];
  const float* bq     = (const float*)d_in[3];
  const float* Wk     = (const float*)d_in[4];
  const float* bk     = (const float*)d_in[5];
  const float* We     = (const float*)d_in[6];
  // d_in[7] = be: additive constant on scores -> softmax-invariant -> unused.

  float* ctx  = (float*)d_out;            // 4*512*256 floats
  float* attn = ctx + 4*512*256;          // 4*512*512 floats (final attention)
  float* EqT  = (float*)d_ws;             // [b][h][q], 524288 floats (2MB)
  float* EkT  = EqT + 524288;             // [b][h][k], 524288 floats (2MB)
  float* pt   = EkT + 524288;             // 4 h-partials, 4x 1048576 floats (16MB)

  proj_kernel  <<<dim3(32, 4, 2), 512, 0, stream>>>(query, values, Wq, bq, Wk, bk, EqT, EkT);
  scores_kernel<<<512, 256, 0, stream>>>(EqT, EkT, We, pt);
  ctx_kernel   <<<256, 512, 0, stream>>>(values, pt, attn, ctx);
}